// Round 9
// baseline (269.465 us; speedup 1.0000x reference)
//
#include <hip/hip_runtime.h>
#include <math.h>

#define B_ 4
#define S_ 2048
#define E_ 1024
#define H_ 16
#define D_ 64

using f32x4 = __attribute__((ext_vector_type(4))) float;
using s16x8 = __attribute__((ext_vector_type(8))) short;

// fp32 -> bf16 bits, round-to-nearest-even
__device__ __forceinline__ unsigned short f2bf(float f) {
    unsigned int u = __float_as_uint(f);
    u = (u + 0x7FFFu + ((u >> 16) & 1u)) >> 16;
    return (unsigned short)u;
}

// pack two fp32 -> one u32 of 2x bf16 (RNE) in ONE VALU op (T12 primitive)
__device__ __forceinline__ unsigned int cvt_pk_bf16(float lo, float hi) {
    unsigned int r;
    asm("v_cvt_pk_bf16_f32 %0, %1, %2" : "=v"(r) : "v"(lo), "v"(hi));
    return r;
}

// raw 2^x (avoid libm range-fixup ops if builtin available)
__device__ __forceinline__ float fast_exp2(float x) {
#if __has_builtin(__builtin_amdgcn_exp2f)
    return __builtin_amdgcn_exp2f(x);
#else
    return exp2f(x);
#endif
}

// async global->LDS DMA, 16B per lane; LDS dest = wave-uniform base + lane*16
__device__ __forceinline__ void load_lds16(const void* g, void* l) {
    __builtin_amdgcn_global_load_lds(
        (const __attribute__((address_space(1))) void*)g,
        (__attribute__((address_space(3))) void*)l, 16, 0, 0);
}

#define WAITV(n) asm volatile("s_waitcnt vmcnt(" #n ")" ::: "memory")
#define WAITL(n) asm volatile("s_waitcnt lgkmcnt(" #n ")" ::: "memory")
#define SCHEDB __builtin_amdgcn_sched_barrier(0)

// Q pre-scale: 1/sqrt(D) * log2(e) -> softmax in base-2 (native v_exp_f32)
#define QSCALE 0.18033688011112042f

// ---------------------------------------------------------------------------
// Merged preprocessing (unchanged from R8): cast_x + transpose_w, dense grid.
// ---------------------------------------------------------------------------
__global__ __launch_bounds__(256)
void preprocess(const float* __restrict__ x,
                const float* __restrict__ wq, const float* __restrict__ wk,
                const float* __restrict__ wv, const float* __restrict__ wo,
                unsigned short* __restrict__ xb,
                unsigned short* __restrict__ Wqkvt, unsigned short* __restrict__ Wot)
{
    const int bid = blockIdx.x;
    const int tid = threadIdx.x;

    if (bid < 4096) {
        const size_t idx = (size_t)bid * 2048 + tid * 8;
        const float4 v0 = *(const float4*)&x[idx];
        const float4 v1 = *(const float4*)&x[idx + 4];
        uint4 p;
        p.x = (unsigned)f2bf(v0.x) | ((unsigned)f2bf(v0.y) << 16);
        p.y = (unsigned)f2bf(v0.z) | ((unsigned)f2bf(v0.w) << 16);
        p.z = (unsigned)f2bf(v1.x) | ((unsigned)f2bf(v1.y) << 16);
        p.w = (unsigned)f2bf(v1.z) | ((unsigned)f2bf(v1.w) << 16);
        *(uint4*)&xb[idx] = p;
        return;
    }

    __shared__ float T[64][68];
    const int b2 = bid - 4096;
    const float* in;
    unsigned short* out;
    int inStride, r0, c0;
    if (b2 < 768) {
        const int z = b2 >> 4;
        const int t = z >> 4, h = z & 15;
        const float* W = (t == 0) ? wq : ((t == 1) ? wk : wv);
        in = W + (size_t)h * (E_ * D_);
        inStride = 64;
        out = Wqkvt + (size_t)(t * 1024 + h * 64) * 1024;
        r0 = (b2 & 15) * 64; c0 = 0;
    } else {
        const int q = b2 - 768;
        in = wo; inStride = 1024;
        out = Wot;
        r0 = (q & 15) * 64; c0 = (q >> 4) * 64;
    }
    #pragma unroll
    for (int i = 0; i < 4; ++i) {
        const int e = tid + i * 256;
        const int row = e >> 4, c4 = e & 15;
        const float4 v = *(const float4*)&in[(size_t)(r0 + row) * inStride + c0 + c4 * 4];
        T[row][c4 * 4 + 0] = v.x; T[row][c4 * 4 + 1] = v.y;
        T[row][c4 * 4 + 2] = v.z; T[row][c4 * 4 + 3] = v.w;
    }
    __syncthreads();
    #pragma unroll
    for (int i = 0; i < 2; ++i) {
        const int e = tid + i * 256;
        const int c = e >> 3, ch = e & 7;
        unsigned short h8[8];
        #pragma unroll
        for (int j = 0; j < 8; ++j) h8[j] = f2bf(T[ch * 8 + j][c]);
        uint4 p;
        p.x = (unsigned)h8[0] | ((unsigned)h8[1] << 16);
        p.y = (unsigned)h8[2] | ((unsigned)h8[3] << 16);
        p.z = (unsigned)h8[4] | ((unsigned)h8[5] << 16);
        p.w = (unsigned)h8[6] | ((unsigned)h8[7] << 16);
        *(uint4*)&out[(size_t)(c0 + c) * 1024 + r0 + ch * 8] = p;
    }
}

// ---------------------------------------------------------------------------
// bf16 MFMA GEMM v7 (unchanged from R5/R8 — best measured: 73 µs MODE0).
// ---------------------------------------------------------------------------
template<int MODE>
__global__ __launch_bounds__(512, 2)
void gemm_mfma(const unsigned short* __restrict__ A,
               const unsigned short* __restrict__ Bt,
               const float* __restrict__ bq, const float* __restrict__ bk,
               const float* __restrict__ bv, const float* __restrict__ bo,
               unsigned short* __restrict__ Qb, unsigned short* __restrict__ Kb,
               unsigned short* __restrict__ Vt, float* __restrict__ Cout)
{
    __shared__ short As[3][128 * 64];
    __shared__ short Bs[3][256 * 64];

    const int tid  = threadIdx.x;
    const int w    = tid >> 6, lane = tid & 63;
    const int g    = lane >> 4, l15 = lane & 15;
    const int wm   = w >> 2, wn = w & 3;
    const int mbase = blockIdx.x * 128;
    const int nbase = blockIdx.y * 256;

    const int srow   = lane >> 3;
    const int schunk = (lane & 7) ^ srow;
    const size_t aoff = (size_t)(mbase + srow) * 1024 + schunk * 8;
    const size_t boff = (size_t)(nbase + srow) * 1024 + schunk * 8;

    f32x4 acc[4][4];
    #pragma unroll
    for (int mt = 0; mt < 4; ++mt)
        #pragma unroll
        for (int nt = 0; nt < 4; ++nt)
            acc[mt][nt] = (f32x4){0.f, 0.f, 0.f, 0.f};

    auto STAGE = [&](int t, int buf) {
        #pragma unroll
        for (int i = 0; i < 2; ++i) {
            const int u = w * 2 + i;
            load_lds16(&A[aoff + (size_t)(u * 8) * 1024 + t * 64], &As[buf][u * 512]);
        }
        #pragma unroll
        for (int i = 0; i < 4; ++i) {
            const int u = w * 4 + i;
            load_lds16(&Bt[boff + (size_t)(u * 8) * 1024 + t * 64], &Bs[buf][u * 512]);
        }
    };

    const int pr  = l15 & 7;
    const int pc0 = (g ^ pr) * 8;
    const int pc1 = ((4 + g) ^ pr) * 8;

    s16x8 a0[4], b0[4], a1[4], b1[4];
    auto LDF = [&](s16x8* af, s16x8* bf, int buf, int pc) {
        #pragma unroll
        for (int mt = 0; mt < 4; ++mt)
            af[mt] = *(const s16x8*)&As[buf][(wm * 64 + mt * 16 + l15) * 64 + pc];
        #pragma unroll
        for (int nt = 0; nt < 4; ++nt)
            bf[nt] = *(const s16x8*)&Bs[buf][(wn * 64 + nt * 16 + l15) * 64 + pc];
    };
    auto MFMA16 = [&](const s16x8* af, const s16x8* bf) {
        __builtin_amdgcn_s_setprio(1);
        #pragma unroll
        for (int mt = 0; mt < 4; ++mt)
            #pragma unroll
            for (int nt = 0; nt < 4; ++nt)
                acc[mt][nt] = __builtin_amdgcn_mfma_f32_16x16x32_bf16(
                    af[mt], bf[nt], acc[mt][nt], 0, 0, 0);
        __builtin_amdgcn_s_setprio(0);
    };

    STAGE(0, 0); STAGE(1, 1);
    WAITV(6);
    __builtin_amdgcn_s_barrier();
    LDF(a0, b0, 0, pc0);

    #pragma unroll 1
    for (int t = 0; t < 16; ++t) {
        const int buf = t % 3;
        LDF(a1, b1, buf, pc1);
        if (t + 2 < 16) STAGE(t + 2, (t + 2) % 3);
        WAITL(8); SCHEDB;
        MFMA16(a0, b0);
        WAITL(0); SCHEDB;
        if (t < 15) {
            if (t < 14) { WAITV(6); } else { WAITV(0); }
            __builtin_amdgcn_s_barrier();
            LDF(a0, b0, (t + 1) % 3, pc0);
            WAITL(8); SCHEDB;
        }
        MFMA16(a1, b1);
    }

    #pragma unroll
    for (int nt = 0; nt < 4; ++nt) {
        const int ncol = nbase + wn * 64 + nt * 16 + l15;
        if (MODE == 0) {
            const int tt = ncol >> 10;
            const int hh = (ncol >> 6) & 15;
            const int d  = ncol & 63;
            const float* bias = (tt == 0) ? bq : ((tt == 1) ? bk : bv);
            const float sc = (tt == 0) ? QSCALE : 1.0f;
            const float bval = bias[hh * 64 + d];
            #pragma unroll
            for (int mt = 0; mt < 4; ++mt)
                #pragma unroll
                for (int r = 0; r < 4; ++r) {
                    const int m = mbase + wm * 64 + mt * 16 + g * 4 + r;
                    const int b = m >> 11, s = m & 2047;
                    const unsigned short val = f2bf((acc[mt][nt][r] + bval) * sc);
                    if (tt == 2)
                        Vt[((size_t)(b * 16 + hh) * 64 + d) * 2048 + s] = val;
                    else {
                        unsigned short* Out = (tt == 0) ? Qb : Kb;
                        Out[((size_t)(b * 16 + hh) * 2048 + s) * 64 + d] = val;
                    }
                }
        } else {
            const float bval = bo[ncol];
            #pragma unroll
            for (int mt = 0; mt < 4; ++mt)
                #pragma unroll
                for (int r = 0; r < 4; ++r) {
                    const int m = mbase + wm * 64 + mt * 16 + g * 4 + r;
                    Cout[(size_t)m * 1024 + ncol] = acc[mt][nt][r] + bval;
                }
        }
    }
}

// ---------------------------------------------------------------------------
// MFMA flash attention v9 — K/V staging via global_load_lds (T4-for-attn).
//   R8 audit: per stage every thread did 2 global uint4 loads + 2 ds_write
//   + reg prefetch; VALU-heavy, 1.2e7 LDS bank-conflict cycles. v9:
//   * K/V tiles [64][64] (pad dropped), double-buffered, staged by exactly
//     2 global_load_lds per wave per stage (wave w owns rows w*8..w*8+7).
//   * Both-sides swizzle (m173/m201): LDS slot p of row r holds logical
//     chunk p^(r&7) via pre-swizzled SOURCE (chunk (l&7)^(l>>3)); reads use
//     physical chunk (g)^(l15&7) / (4+g)^(l15&7) -> 8-lane b128 groups
//     cover all 32 banks, conflict-free (same algebra as the GEMM, R2-R8).
//   * Pipeline distance 1: ISSUE(t+1) right after the barrier; WAITV(0)
//     just before the next barrier (t's DMAs had a full compute phase).
//   * P path (LDK=72, cvt_pk, ones-MFMA row-sum) unchanged from R4.
// ---------------------------------------------------------------------------
#define LDK 72
__global__ __launch_bounds__(512, 2)
void attn_mfma(const unsigned short* __restrict__ Qb,
               const unsigned short* __restrict__ Kb,
               const unsigned short* __restrict__ Vt,
               unsigned short* __restrict__ O)
{
    __shared__ short Kls[2][64 * 64];
    __shared__ short Vls[2][64 * 64];        // [d][key]
    __shared__ short Pls[8][16 * LDK];       // per-wave P [query][key]

    const int tid  = threadIdx.x;
    const int w    = tid >> 6;               // 0..7
    const int lane = tid & 63;
    const int g    = lane >> 4;
    const int l15  = lane & 15;
    const int j    = blockIdx.x;             // 0..7 (light tile index)
    const int j2   = 15 - j;                 // heavy tile index
    const int h    = blockIdx.y;
    const int b    = blockIdx.z;

    const size_t hb = (size_t)(b * 16 + h) * (2048 * 64);
    const int qH = j2 * 128 + w * 16;        // this wave's heavy query base
    const int qL = j * 128 + w * 16;         // this wave's light query base

    s16x8 aqH[2], aqL[2];
    {
        const int rh = qH + l15, rl = qL + l15;
        aqH[0] = *(const s16x8*)&Qb[hb + (size_t)rh * 64 + g * 8];
        aqH[1] = *(const s16x8*)&Qb[hb + (size_t)rh * 64 + 32 + g * 8];
        aqL[0] = *(const s16x8*)&Qb[hb + (size_t)rl * 64 + g * 8];
        aqL[1] = *(const s16x8*)&Qb[hb + (size_t)rl * 64 + 32 + g * 8];
    }

    // all-ones bf16 A-frag for the row-sum MFMA (bf16 1.0 = 0x3F80)
    const s16x8 ones = (s16x8){(short)0x3F80, (short)0x3F80, (short)0x3F80,
                               (short)0x3F80, (short)0x3F80, (short)0x3F80,
                               (short)0x3F80, (short)0x3F80};

    f32x4 lsumHa = (f32x4){0.f,0.f,0.f,0.f};
    f32x4 lsumLa = (f32x4){0.f,0.f,0.f,0.f};
    f32x4 OH[4], OL[4];                      // O^T: col query, rows d
    #pragma unroll
    for (int nt = 0; nt < 4; ++nt) { OH[nt] = (f32x4){0.f,0.f,0.f,0.f}; OL[nt] = (f32x4){0.f,0.f,0.f,0.f}; }

    const int stages      = 32 - 2 * j;
    const int lightStages = 2 * j + 2;

    // K/V DMA staging: wave w owns rows w*8..w*8+7 of the 64-row tile.
    const int srow8  = lane >> 3;            // 0..7 row within slab
    const int schunk = (lane & 7) ^ srow8;   // pre-swizzled source chunk
    const int krow   = w * 8 + srow8;        // 0..63 row in tile
    auto ISSUE = [&](int t, int buf) {
        const int t0 = t * 64;
        load_lds16(&Kb[hb + (size_t)(t0 + krow) * 64 + schunk * 8],
                   &Kls[buf][w * 512]);
        load_lds16(&Vt[hb + (size_t)krow * 2048 + t0 + schunk * 8],
                   &Vls[buf][w * 512]);
    };

    ISSUE(0, 0);                              // prologue

    const int rswz = l15 & 7;                 // read-side row swizzle bits
    const int pcA  = (g ^ rswz) * 8;          // logical chunk g
    const int pcB  = ((4 + g) ^ rswz) * 8;    // logical chunk 4+g

    for (int t = 0; t < stages; ++t) {
        const int buf = t & 1;
        WAITV(0); SCHEDB;                     // own K/V(t) DMAs landed
        __builtin_amdgcn_s_barrier();         // publish tile t; licenses buf^1
        if (t + 1 < stages) ISSUE(t + 1, buf ^ 1);
        const int t0 = t * 64;

        #pragma unroll
        for (int half = 0; half < 2; ++half) {
            if (half == 1 && t >= lightStages) break;
            const s16x8* aq   = (half == 0) ? aqH : aqL;
            const int qbase   = (half == 0) ? qH : qL;
            f32x4* Oacc       = (half == 0) ? OH : OL;
            f32x4* lsa        = (half == 0) ? &lsumHa : &lsumLa;

            // ---- S^T = K * Q^T : Sf[ct][r] = S[query=l15][key=t0+ct*16+g*4+r]
            f32x4 Sf[4];
            #pragma unroll
            for (int ct = 0; ct < 4; ++ct) {
                f32x4 acc = (f32x4){0.f, 0.f, 0.f, 0.f};
                const s16x8 bk0 = *(const s16x8*)&Kls[buf][(ct * 16 + l15) * 64 + pcA];
                const s16x8 bk1 = *(const s16x8*)&Kls[buf][(ct * 16 + l15) * 64 + pcB];
                acc = __builtin_amdgcn_mfma_f32_16x16x32_bf16(bk0, aq[0], acc, 0, 0, 0);
                acc = __builtin_amdgcn_mfma_f32_16x16x32_bf16(bk1, aq[1], acc, 0, 0, 0);
                Sf[ct] = acc;
            }

            // ---- causal mask (diagonal tiles only) ----
            if (t0 + 63 > qbase) {
                const int query = qbase + l15;
                #pragma unroll
                for (int ct = 0; ct < 4; ++ct) {
                    const int kbase = t0 + ct * 16 + g * 4;
                    #pragma unroll
                    for (int r = 0; r < 4; ++r)
                        if (kbase + r > query) Sf[ct][r] = -1e30f;
                }
            }

            // ---- p = exp2(s) ----
            #pragma unroll
            for (int ct = 0; ct < 4; ++ct)
                #pragma unroll
                for (int r = 0; r < 4; ++r) Sf[ct][r] = fast_exp2(Sf[ct][r]);

            // ---- write P[query][key]: cvt_pk (1 VALU per pair) -> b64 ----
            #pragma unroll
            for (int ct = 0; ct < 4; ++ct) {
                uint2 pw;
                pw.x = cvt_pk_bf16(Sf[ct][0], Sf[ct][1]);
                pw.y = cvt_pk_bf16(Sf[ct][2], Sf[ct][3]);
                *(uint2*)&Pls[w][l15 * LDK + ct * 16 + g * 4] = pw;
            }

            // ---- PV: O^T += V^T * P^T; l += 1 * P^T (ones-MFMA row-sum) ----
            const s16x8 pf0 = *(const s16x8*)&Pls[w][l15 * LDK + g * 8];
            const s16x8 pf1 = *(const s16x8*)&Pls[w][l15 * LDK + 32 + g * 8];
            *lsa = __builtin_amdgcn_mfma_f32_16x16x32_bf16(ones, pf0, *lsa, 0, 0, 0);
            *lsa = __builtin_amdgcn_mfma_f32_16x16x32_bf16(ones, pf1, *lsa, 0, 0, 0);
            #pragma unroll
            for (int nt = 0; nt < 4; ++nt) {
                const s16x8 bv0 = *(const s16x8*)&Vls[buf][(nt * 16 + l15) * 64 + pcA];
                const s16x8 bv1 = *(const s16x8*)&Vls[buf][(nt * 16 + l15) * 64 + pcB];
                Oacc[nt] = __builtin_amdgcn_mfma_f32_16x16x32_bf16(bv0, pf0, Oacc[nt], 0, 0, 0);
                Oacc[nt] = __builtin_amdgcn_mfma_f32_16x16x32_bf16(bv1, pf1, Oacc[nt], 0, 0, 0);
            }
        }
    }

    // ---- epilogue: l is complete per-query in every acc reg; store O ----
    const float invH = 1.0f / lsumHa[0];
    const float invL = 1.0f / lsumLa[0];

    #pragma unroll
    for (int half = 0; half < 2; ++half) {
        const f32x4* Oacc = (half == 0) ? OH : OL;
        const float  inv  = (half == 0) ? invH : invL;
        const int query   = ((half == 0) ? qH : qL) + l15;
        #pragma unroll
        for (int nt = 0; nt < 4; ++nt) {
            uint2 pk;
            pk.x = cvt_pk_bf16(Oacc[nt][0] * inv, Oacc[nt][1] * inv);
            pk.y = cvt_pk_bf16(Oacc[nt][2] * inv, Oacc[nt][3] * inv);
            *(uint2*)&O[(size_t)(b * 2048 + query) * 1024 + h * 64 + nt * 16 + g * 4] = pk;
        }
    }
}

// ---------------------------------------------------------------------------
// ws (ushort elems): xb 8M | Wqkvt 3M | Wot 1M | Qb/Kb/Vt 8M each | Ob 8M
// ---------------------------------------------------------------------------
extern "C" void kernel_launch(void* const* d_in, const int* in_sizes, int n_in,
                              void* d_out, int out_size, void* d_ws, size_t ws_size,
                              hipStream_t stream) {
    const float* x  = (const float*)d_in[0];
    const float* wq = (const float*)d_in[1];
    const float* bq = (const float*)d_in[2];
    const float* wk = (const float*)d_in[3];
    const float* bk = (const float*)d_in[4];
    const float* wv = (const float*)d_in[5];
    const float* bv = (const float*)d_in[6];
    const float* wo = (const float*)d_in[7];
    const float* bo = (const float*)d_in[8];
    float* out = (float*)d_out;

    const size_t hsz = (size_t)B_ * H_ * S_ * D_;        // 8388608
    unsigned short* xb    = (unsigned short*)d_ws;
    unsigned short* Wqkvt = xb + hsz;
    unsigned short* Wot   = Wqkvt + (size_t)3072 * 1024;
    unsigned short* Qb    = Wot + (size_t)1024 * 1024;
    unsigned short* Kb    = Qb + hsz;
    unsigned short* Vt    = Kb + hsz;
    unsigned short* Ob    = Vt + hsz;

    preprocess<<<5120, 256, 0, stream>>>(x, wq, wk, wv, wo, xb, Wqkvt, Wot);
    gemm_mfma<0><<<dim3(64, 12), 512, 0, stream>>>(
        xb, Wqkvt, bq, bk, bv, nullptr, Qb, Kb, Vt, nullptr);
    attn_mfma<<<dim3(8, H_, B_), 512, 0, stream>>>(Qb, Kb, Vt, Ob);
    gemm_mfma<1><<<dim3(64, 4), 512, 0, stream>>>(
        Ob, Wot, nullptr, nullptr, nullptr, bo, nullptr, nullptr, nullptr, out);
}

// Round 10
// 268.902 us; speedup vs baseline: 1.0021x; 1.0021x over previous
//
#include <hip/hip_runtime.h>
#include <math.h>

#define B_ 4
#define S_ 2048
#define E_ 1024
#define H_ 16
#define D_ 64

using f32x4 = __attribute__((ext_vector_type(4))) float;
using s16x8 = __attribute__((ext_vector_type(8))) short;

// fp32 -> bf16 bits, round-to-nearest-even
__device__ __forceinline__ unsigned short f2bf(float f) {
    unsigned int u = __float_as_uint(f);
    u = (u + 0x7FFFu + ((u >> 16) & 1u)) >> 16;
    return (unsigned short)u;
}

// pack two fp32 -> one u32 of 2x bf16 (RNE) in ONE VALU op (T12 primitive)
__device__ __forceinline__ unsigned int cvt_pk_bf16(float lo, float hi) {
    unsigned int r;
    asm("v_cvt_pk_bf16_f32 %0, %1, %2" : "=v"(r) : "v"(lo), "v"(hi));
    return r;
}

// raw 2^x (avoid libm range-fixup ops if builtin available)
__device__ __forceinline__ float fast_exp2(float x) {
#if __has_builtin(__builtin_amdgcn_exp2f)
    return __builtin_amdgcn_exp2f(x);
#else
    return exp2f(x);
#endif
}

// async global->LDS DMA, 16B per lane; LDS dest = wave-uniform base + lane*16
__device__ __forceinline__ void load_lds16(const void* g, void* l) {
    __builtin_amdgcn_global_load_lds(
        (const __attribute__((address_space(1))) void*)g,
        (__attribute__((address_space(3))) void*)l, 16, 0, 0);
}

#define WAITV(n) asm volatile("s_waitcnt vmcnt(" #n ")" ::: "memory")
#define WAITL(n) asm volatile("s_waitcnt lgkmcnt(" #n ")" ::: "memory")
#define SCHEDB __builtin_amdgcn_sched_barrier(0)

// Q pre-scale: 1/sqrt(D) * log2(e) -> softmax in base-2 (native v_exp_f32)
#define QSCALE 0.18033688011112042f

// ---------------------------------------------------------------------------
// Merged preprocessing (unchanged from R8): cast_x + transpose_w, dense grid.
// ---------------------------------------------------------------------------
__global__ __launch_bounds__(256)
void preprocess(const float* __restrict__ x,
                const float* __restrict__ wq, const float* __restrict__ wk,
                const float* __restrict__ wv, const float* __restrict__ wo,
                unsigned short* __restrict__ xb,
                unsigned short* __restrict__ Wqkvt, unsigned short* __restrict__ Wot)
{
    const int bid = blockIdx.x;
    const int tid = threadIdx.x;

    if (bid < 4096) {
        const size_t idx = (size_t)bid * 2048 + tid * 8;
        const float4 v0 = *(const float4*)&x[idx];
        const float4 v1 = *(const float4*)&x[idx + 4];
        uint4 p;
        p.x = (unsigned)f2bf(v0.x) | ((unsigned)f2bf(v0.y) << 16);
        p.y = (unsigned)f2bf(v0.z) | ((unsigned)f2bf(v0.w) << 16);
        p.z = (unsigned)f2bf(v1.x) | ((unsigned)f2bf(v1.y) << 16);
        p.w = (unsigned)f2bf(v1.z) | ((unsigned)f2bf(v1.w) << 16);
        *(uint4*)&xb[idx] = p;
        return;
    }

    __shared__ float T[64][68];
    const int b2 = bid - 4096;
    const float* in;
    unsigned short* out;
    int inStride, r0, c0;
    if (b2 < 768) {
        const int z = b2 >> 4;
        const int t = z >> 4, h = z & 15;
        const float* W = (t == 0) ? wq : ((t == 1) ? wk : wv);
        in = W + (size_t)h * (E_ * D_);
        inStride = 64;
        out = Wqkvt + (size_t)(t * 1024 + h * 64) * 1024;
        r0 = (b2 & 15) * 64; c0 = 0;
    } else {
        const int q = b2 - 768;
        in = wo; inStride = 1024;
        out = Wot;
        r0 = (q & 15) * 64; c0 = (q >> 4) * 64;
    }
    #pragma unroll
    for (int i = 0; i < 4; ++i) {
        const int e = tid + i * 256;
        const int row = e >> 4, c4 = e & 15;
        const float4 v = *(const float4*)&in[(size_t)(r0 + row) * inStride + c0 + c4 * 4];
        T[row][c4 * 4 + 0] = v.x; T[row][c4 * 4 + 1] = v.y;
        T[row][c4 * 4 + 2] = v.z; T[row][c4 * 4 + 3] = v.w;
    }
    __syncthreads();
    #pragma unroll
    for (int i = 0; i < 2; ++i) {
        const int e = tid + i * 256;
        const int c = e >> 3, ch = e & 7;
        unsigned short h8[8];
        #pragma unroll
        for (int j = 0; j < 8; ++j) h8[j] = f2bf(T[ch * 8 + j][c]);
        uint4 p;
        p.x = (unsigned)h8[0] | ((unsigned)h8[1] << 16);
        p.y = (unsigned)h8[2] | ((unsigned)h8[3] << 16);
        p.z = (unsigned)h8[4] | ((unsigned)h8[5] << 16);
        p.w = (unsigned)h8[6] | ((unsigned)h8[7] << 16);
        *(uint4*)&out[(size_t)(c0 + c) * 1024 + r0 + ch * 8] = p;
    }
}

// ---------------------------------------------------------------------------
// bf16 MFMA GEMM v7 (unchanged from R5/R8 — best measured: 73 µs MODE0).
// ---------------------------------------------------------------------------
template<int MODE>
__global__ __launch_bounds__(512, 2)
void gemm_mfma(const unsigned short* __restrict__ A,
               const unsigned short* __restrict__ Bt,
               const float* __restrict__ bq, const float* __restrict__ bk,
               const float* __restrict__ bv, const float* __restrict__ bo,
               unsigned short* __restrict__ Qb, unsigned short* __restrict__ Kb,
               unsigned short* __restrict__ Vt, float* __restrict__ Cout)
{
    __shared__ short As[3][128 * 64];
    __shared__ short Bs[3][256 * 64];

    const int tid  = threadIdx.x;
    const int w    = tid >> 6, lane = tid & 63;
    const int g    = lane >> 4, l15 = lane & 15;
    const int wm   = w >> 2, wn = w & 3;
    const int mbase = blockIdx.x * 128;
    const int nbase = blockIdx.y * 256;

    const int srow   = lane >> 3;
    const int schunk = (lane & 7) ^ srow;
    const size_t aoff = (size_t)(mbase + srow) * 1024 + schunk * 8;
    const size_t boff = (size_t)(nbase + srow) * 1024 + schunk * 8;

    f32x4 acc[4][4];
    #pragma unroll
    for (int mt = 0; mt < 4; ++mt)
        #pragma unroll
        for (int nt = 0; nt < 4; ++nt)
            acc[mt][nt] = (f32x4){0.f, 0.f, 0.f, 0.f};

    auto STAGE = [&](int t, int buf) {
        #pragma unroll
        for (int i = 0; i < 2; ++i) {
            const int u = w * 2 + i;
            load_lds16(&A[aoff + (size_t)(u * 8) * 1024 + t * 64], &As[buf][u * 512]);
        }
        #pragma unroll
        for (int i = 0; i < 4; ++i) {
            const int u = w * 4 + i;
            load_lds16(&Bt[boff + (size_t)(u * 8) * 1024 + t * 64], &Bs[buf][u * 512]);
        }
    };

    const int pr  = l15 & 7;
    const int pc0 = (g ^ pr) * 8;
    const int pc1 = ((4 + g) ^ pr) * 8;

    s16x8 a0[4], b0[4], a1[4], b1[4];
    auto LDF = [&](s16x8* af, s16x8* bf, int buf, int pc) {
        #pragma unroll
        for (int mt = 0; mt < 4; ++mt)
            af[mt] = *(const s16x8*)&As[buf][(wm * 64 + mt * 16 + l15) * 64 + pc];
        #pragma unroll
        for (int nt = 0; nt < 4; ++nt)
            bf[nt] = *(const s16x8*)&Bs[buf][(wn * 64 + nt * 16 + l15) * 64 + pc];
    };
    auto MFMA16 = [&](const s16x8* af, const s16x8* bf) {
        __builtin_amdgcn_s_setprio(1);
        #pragma unroll
        for (int mt = 0; mt < 4; ++mt)
            #pragma unroll
            for (int nt = 0; nt < 4; ++nt)
                acc[mt][nt] = __builtin_amdgcn_mfma_f32_16x16x32_bf16(
                    af[mt], bf[nt], acc[mt][nt], 0, 0, 0);
        __builtin_amdgcn_s_setprio(0);
    };

    STAGE(0, 0); STAGE(1, 1);
    WAITV(6);
    __builtin_amdgcn_s_barrier();
    LDF(a0, b0, 0, pc0);

    #pragma unroll 1
    for (int t = 0; t < 16; ++t) {
        const int buf = t % 3;
        LDF(a1, b1, buf, pc1);
        if (t + 2 < 16) STAGE(t + 2, (t + 2) % 3);
        WAITL(8); SCHEDB;
        MFMA16(a0, b0);
        WAITL(0); SCHEDB;
        if (t < 15) {
            if (t < 14) { WAITV(6); } else { WAITV(0); }
            __builtin_amdgcn_s_barrier();
            LDF(a0, b0, (t + 1) % 3, pc0);
            WAITL(8); SCHEDB;
        }
        MFMA16(a1, b1);
    }

    #pragma unroll
    for (int nt = 0; nt < 4; ++nt) {
        const int ncol = nbase + wn * 64 + nt * 16 + l15;
        if (MODE == 0) {
            const int tt = ncol >> 10;
            const int hh = (ncol >> 6) & 15;
            const int d  = ncol & 63;
            const float* bias = (tt == 0) ? bq : ((tt == 1) ? bk : bv);
            const float sc = (tt == 0) ? QSCALE : 1.0f;
            const float bval = bias[hh * 64 + d];
            #pragma unroll
            for (int mt = 0; mt < 4; ++mt)
                #pragma unroll
                for (int r = 0; r < 4; ++r) {
                    const int m = mbase + wm * 64 + mt * 16 + g * 4 + r;
                    const int b = m >> 11, s = m & 2047;
                    const unsigned short val = f2bf((acc[mt][nt][r] + bval) * sc);
                    if (tt == 2)
                        Vt[((size_t)(b * 16 + hh) * 64 + d) * 2048 + s] = val;
                    else {
                        unsigned short* Out = (tt == 0) ? Qb : Kb;
                        Out[((size_t)(b * 16 + hh) * 2048 + s) * 64 + d] = val;
                    }
                }
        } else {
            const float bval = bo[ncol];
            #pragma unroll
            for (int mt = 0; mt < 4; ++mt)
                #pragma unroll
                for (int r = 0; r < 4; ++r) {
                    const int m = mbase + wm * 64 + mt * 16 + g * 4 + r;
                    Cout[(size_t)m * 1024 + ncol] = acc[mt][nt][r] + bval;
                }
        }
    }
}

// ---------------------------------------------------------------------------
// MFMA flash attention v10 — R8's v8 reg-staged structure (reverted from the
// R9 DMA experiment: -12 µs regression, VGPR 64->80) with ONE change:
//   __syncthreads() -> { WAITL(0); sched_barrier; raw s_barrier }.
//   __syncthreads compiles to s_waitcnt vmcnt(0) lgkmcnt(0) + s_barrier,
//   which drained the kreg/vreg PREFETCH loads at every stage barrier --
//   exposing raw L2/HBM latency ~34x per block. The barrier only needs the
//   ds_writes published (lgkmcnt(0)); the vm prefetch loads now stay in
//   flight across the barrier and drain at their ds_write use next stage,
//   gaining a full compute phase of hiding. WAR safe: double-buffer means
//   the buffer written at stage t was last read at stage t-2.
// ---------------------------------------------------------------------------
#define LDK 72
__global__ __launch_bounds__(512, 2)
void attn_mfma(const unsigned short* __restrict__ Qb,
               const unsigned short* __restrict__ Kb,
               const unsigned short* __restrict__ Vt,
               unsigned short* __restrict__ O)
{
    __shared__ short Kls[2][64 * LDK];
    __shared__ short Vls[2][64 * LDK];       // [d][key]
    __shared__ short Pls[8][16 * LDK];       // per-wave P [query][key]

    const int tid  = threadIdx.x;
    const int w    = tid >> 6;               // 0..7
    const int lane = tid & 63;
    const int g    = lane >> 4;
    const int l15  = lane & 15;
    const int j    = blockIdx.x;             // 0..7 (light tile index)
    const int j2   = 15 - j;                 // heavy tile index
    const int h    = blockIdx.y;
    const int b    = blockIdx.z;

    const size_t hb = (size_t)(b * 16 + h) * (2048 * 64);
    const int qH = j2 * 128 + w * 16;        // this wave's heavy query base
    const int qL = j * 128 + w * 16;         // this wave's light query base

    s16x8 aqH[2], aqL[2];
    {
        const int rh = qH + l15, rl = qL + l15;
        aqH[0] = *(const s16x8*)&Qb[hb + (size_t)rh * 64 + g * 8];
        aqH[1] = *(const s16x8*)&Qb[hb + (size_t)rh * 64 + 32 + g * 8];
        aqL[0] = *(const s16x8*)&Qb[hb + (size_t)rl * 64 + g * 8];
        aqL[1] = *(const s16x8*)&Qb[hb + (size_t)rl * 64 + 32 + g * 8];
    }

    // all-ones bf16 A-frag for the row-sum MFMA (bf16 1.0 = 0x3F80)
    const s16x8 ones = (s16x8){(short)0x3F80, (short)0x3F80, (short)0x3F80,
                               (short)0x3F80, (short)0x3F80, (short)0x3F80,
                               (short)0x3F80, (short)0x3F80};

    f32x4 lsumHa = (f32x4){0.f,0.f,0.f,0.f};
    f32x4 lsumLa = (f32x4){0.f,0.f,0.f,0.f};
    f32x4 OH[4], OL[4];                      // O^T: col query, rows d
    #pragma unroll
    for (int nt = 0; nt < 4; ++nt) { OH[nt] = (f32x4){0.f,0.f,0.f,0.f}; OL[nt] = (f32x4){0.f,0.f,0.f,0.f}; }

    const int stages      = 32 - 2 * j;
    const int lightStages = 2 * j + 2;

    const int srow = tid >> 3, spart = tid & 7;
    uint4 kreg = *(const uint4*)&Kb[hb + (size_t)srow * 64 + spart * 8];
    uint4 vreg = *(const uint4*)&Vt[hb + (size_t)srow * 2048 + spart * 8];

    for (int t = 0; t < stages; ++t) {
        const int t0  = t * 64;
        const int buf = t & 1;
        *(uint4*)&Kls[buf][srow * LDK + spart * 8] = kreg;
        *(uint4*)&Vls[buf][srow * LDK + spart * 8] = vreg;
        if (t + 1 < stages) {
            kreg = *(const uint4*)&Kb[hb + (size_t)(t0 + 64 + srow) * 64 + spart * 8];
            vreg = *(const uint4*)&Vt[hb + (size_t)srow * 2048 + t0 + 64 + spart * 8];
        }
        // publish ds_writes only; leave the vm prefetch loads in flight
        WAITL(0); SCHEDB;
        __builtin_amdgcn_s_barrier();

        #pragma unroll
        for (int half = 0; half < 2; ++half) {
            if (half == 1 && t >= lightStages) break;
            const s16x8* aq   = (half == 0) ? aqH : aqL;
            const int qbase   = (half == 0) ? qH : qL;
            f32x4* Oacc       = (half == 0) ? OH : OL;
            f32x4* lsa        = (half == 0) ? &lsumHa : &lsumLa;

            // ---- S^T = K * Q^T : Sf[ct][r] = S[query=l15][key=t0+ct*16+g*4+r]
            f32x4 Sf[4];
            #pragma unroll
            for (int ct = 0; ct < 4; ++ct) {
                f32x4 acc = (f32x4){0.f, 0.f, 0.f, 0.f};
                const s16x8 bk0 = *(const s16x8*)&Kls[buf][(ct * 16 + l15) * LDK + g * 8];
                const s16x8 bk1 = *(const s16x8*)&Kls[buf][(ct * 16 + l15) * LDK + 32 + g * 8];
                acc = __builtin_amdgcn_mfma_f32_16x16x32_bf16(bk0, aq[0], acc, 0, 0, 0);
                acc = __builtin_amdgcn_mfma_f32_16x16x32_bf16(bk1, aq[1], acc, 0, 0, 0);
                Sf[ct] = acc;
            }

            // ---- causal mask (diagonal tiles only) ----
            if (t0 + 63 > qbase) {
                const int query = qbase + l15;
                #pragma unroll
                for (int ct = 0; ct < 4; ++ct) {
                    const int kbase = t0 + ct * 16 + g * 4;
                    #pragma unroll
                    for (int r = 0; r < 4; ++r)
                        if (kbase + r > query) Sf[ct][r] = -1e30f;
                }
            }

            // ---- p = exp2(s) ----
            #pragma unroll
            for (int ct = 0; ct < 4; ++ct)
                #pragma unroll
                for (int r = 0; r < 4; ++r) Sf[ct][r] = fast_exp2(Sf[ct][r]);

            // ---- write P[query][key]: cvt_pk (1 VALU per pair) -> b64 ----
            #pragma unroll
            for (int ct = 0; ct < 4; ++ct) {
                uint2 pw;
                pw.x = cvt_pk_bf16(Sf[ct][0], Sf[ct][1]);
                pw.y = cvt_pk_bf16(Sf[ct][2], Sf[ct][3]);
                *(uint2*)&Pls[w][l15 * LDK + ct * 16 + g * 4] = pw;
            }

            // ---- PV: O^T += V^T * P^T; l += 1 * P^T (ones-MFMA row-sum) ----
            const s16x8 pf0 = *(const s16x8*)&Pls[w][l15 * LDK + g * 8];
            const s16x8 pf1 = *(const s16x8*)&Pls[w][l15 * LDK + 32 + g * 8];
            *lsa = __builtin_amdgcn_mfma_f32_16x16x32_bf16(ones, pf0, *lsa, 0, 0, 0);
            *lsa = __builtin_amdgcn_mfma_f32_16x16x32_bf16(ones, pf1, *lsa, 0, 0, 0);
            #pragma unroll
            for (int nt = 0; nt < 4; ++nt) {
                const s16x8 bv0 = *(const s16x8*)&Vls[buf][(nt * 16 + l15) * LDK + g * 8];
                const s16x8 bv1 = *(const s16x8*)&Vls[buf][(nt * 16 + l15) * LDK + 32 + g * 8];
                Oacc[nt] = __builtin_amdgcn_mfma_f32_16x16x32_bf16(bv0, pf0, Oacc[nt], 0, 0, 0);
                Oacc[nt] = __builtin_amdgcn_mfma_f32_16x16x32_bf16(bv1, pf1, Oacc[nt], 0, 0, 0);
            }
        }
    }

    // ---- epilogue: l is complete per-query in every acc reg; store O ----
    const float invH = 1.0f / lsumHa[0];
    const float invL = 1.0f / lsumLa[0];

    #pragma unroll
    for (int half = 0; half < 2; ++half) {
        const f32x4* Oacc = (half == 0) ? OH : OL;
        const float  inv  = (half == 0) ? invH : invL;
        const int query   = ((half == 0) ? qH : qL) + l15;
        #pragma unroll
        for (int nt = 0; nt < 4; ++nt) {
            uint2 pk;
            pk.x = cvt_pk_bf16(Oacc[nt][0] * inv, Oacc[nt][1] * inv);
            pk.y = cvt_pk_bf16(Oacc[nt][2] * inv, Oacc[nt][3] * inv);
            *(uint2*)&O[(size_t)(b * 2048 + query) * 1024 + h * 64 + nt * 16 + g * 4] = pk;
        }
    }
}

// ---------------------------------------------------------------------------
// ws (ushort elems): xb 8M | Wqkvt 3M | Wot 1M | Qb/Kb/Vt 8M each | Ob 8M
// ---------------------------------------------------------------------------
extern "C" void kernel_launch(void* const* d_in, const int* in_sizes, int n_in,
                              void* d_out, int out_size, void* d_ws, size_t ws_size,
                              hipStream_t stream) {
    const float* x  = (const float*)d_in[0];
    const float* wq = (const float*)d_in[1];
    const float* bq = (const float*)d_in[2];
    const float* wk = (const float*)d_in[3];
    const float* bk = (const float*)d_in[4];
    const float* wv = (const float*)d_in[5];
    const float* bv = (const float*)d_in[6];
    const float* wo = (const float*)d_in[7];
    const float* bo = (const float*)d_in[8];
    float* out = (float*)d_out;

    const size_t hsz = (size_t)B_ * H_ * S_ * D_;        // 8388608
    unsigned short* xb    = (unsigned short*)d_ws;
    unsigned short* Wqkvt = xb + hsz;
    unsigned short* Wot   = Wqkvt + (size_t)3072 * 1024;
    unsigned short* Qb    = Wot + (size_t)1024 * 1024;
    unsigned short* Kb    = Qb + hsz;
    unsigned short* Vt    = Kb + hsz;
    unsigned short* Ob    = Vt + hsz;

    preprocess<<<5120, 256, 0, stream>>>(x, wq, wk, wv, wo, xb, Wqkvt, Wot);
    gemm_mfma<0><<<dim3(64, 12), 512, 0, stream>>>(
        xb, Wqkvt, bq, bk, bv, nullptr, Qb, Kb, Vt, nullptr);
    attn_mfma<<<dim3(8, H_, B_), 512, 0, stream>>>(Qb, Kb, Vt, Ob);
    gemm_mfma<1><<<dim3(64, 4), 512, 0, stream>>>(
        Ob, Wot, nullptr, nullptr, nullptr, bo, nullptr, nullptr, nullptr, out);
}

// Round 11
// 254.335 us; speedup vs baseline: 1.0595x; 1.0573x over previous
//
#include <hip/hip_runtime.h>
#include <math.h>

#define B_ 4
#define S_ 2048
#define E_ 1024
#define H_ 16
#define D_ 64

using f32x4 = __attribute__((ext_vector_type(4))) float;
using s16x8 = __attribute__((ext_vector_type(8))) short;

// fp32 -> bf16 bits, round-to-nearest-even
__device__ __forceinline__ unsigned short f2bf(float f) {
    unsigned int u = __float_as_uint(f);
    u = (u + 0x7FFFu + ((u >> 16) & 1u)) >> 16;
    return (unsigned short)u;
}

// pack two fp32 -> one u32 of 2x bf16 (RNE) in ONE VALU op (T12 primitive)
__device__ __forceinline__ unsigned int cvt_pk_bf16(float lo, float hi) {
    unsigned int r;
    asm("v_cvt_pk_bf16_f32 %0, %1, %2" : "=v"(r) : "v"(lo), "v"(hi));
    return r;
}

// raw 2^x (avoid libm range-fixup ops if builtin available)
__device__ __forceinline__ float fast_exp2(float x) {
#if __has_builtin(__builtin_amdgcn_exp2f)
    return __builtin_amdgcn_exp2f(x);
#else
    return exp2f(x);
#endif
}

// async global->LDS DMA, 16B per lane; LDS dest = wave-uniform base + lane*16
__device__ __forceinline__ void load_lds16(const void* g, void* l) {
    __builtin_amdgcn_global_load_lds(
        (const __attribute__((address_space(1))) void*)g,
        (__attribute__((address_space(3))) void*)l, 16, 0, 0);
}

#define WAITV(n) asm volatile("s_waitcnt vmcnt(" #n ")" ::: "memory")
#define WAITL(n) asm volatile("s_waitcnt lgkmcnt(" #n ")" ::: "memory")
#define SCHEDB __builtin_amdgcn_sched_barrier(0)

// Q pre-scale: 1/sqrt(D) * log2(e) -> softmax in base-2 (native v_exp_f32)
#define QSCALE 0.18033688011112042f

// ---------------------------------------------------------------------------
// Merged preprocessing (R8, best measured): cast_x + transpose_w, dense grid.
// ---------------------------------------------------------------------------
__global__ __launch_bounds__(256)
void preprocess(const float* __restrict__ x,
                const float* __restrict__ wq, const float* __restrict__ wk,
                const float* __restrict__ wv, const float* __restrict__ wo,
                unsigned short* __restrict__ xb,
                unsigned short* __restrict__ Wqkvt, unsigned short* __restrict__ Wot)
{
    const int bid = blockIdx.x;
    const int tid = threadIdx.x;

    if (bid < 4096) {
        const size_t idx = (size_t)bid * 2048 + tid * 8;
        const float4 v0 = *(const float4*)&x[idx];
        const float4 v1 = *(const float4*)&x[idx + 4];
        uint4 p;
        p.x = (unsigned)f2bf(v0.x) | ((unsigned)f2bf(v0.y) << 16);
        p.y = (unsigned)f2bf(v0.z) | ((unsigned)f2bf(v0.w) << 16);
        p.z = (unsigned)f2bf(v1.x) | ((unsigned)f2bf(v1.y) << 16);
        p.w = (unsigned)f2bf(v1.z) | ((unsigned)f2bf(v1.w) << 16);
        *(uint4*)&xb[idx] = p;
        return;
    }

    __shared__ float T[64][68];
    const int b2 = bid - 4096;
    const float* in;
    unsigned short* out;
    int inStride, r0, c0;
    if (b2 < 768) {
        const int z = b2 >> 4;
        const int t = z >> 4, h = z & 15;
        const float* W = (t == 0) ? wq : ((t == 1) ? wk : wv);
        in = W + (size_t)h * (E_ * D_);
        inStride = 64;
        out = Wqkvt + (size_t)(t * 1024 + h * 64) * 1024;
        r0 = (b2 & 15) * 64; c0 = 0;
    } else {
        const int q = b2 - 768;
        in = wo; inStride = 1024;
        out = Wot;
        r0 = (q & 15) * 64; c0 = (q >> 4) * 64;
    }
    #pragma unroll
    for (int i = 0; i < 4; ++i) {
        const int e = tid + i * 256;
        const int row = e >> 4, c4 = e & 15;
        const float4 v = *(const float4*)&in[(size_t)(r0 + row) * inStride + c0 + c4 * 4];
        T[row][c4 * 4 + 0] = v.x; T[row][c4 * 4 + 1] = v.y;
        T[row][c4 * 4 + 2] = v.z; T[row][c4 * 4 + 3] = v.w;
    }
    __syncthreads();
    #pragma unroll
    for (int i = 0; i < 2; ++i) {
        const int e = tid + i * 256;
        const int c = e >> 3, ch = e & 7;
        unsigned short h8[8];
        #pragma unroll
        for (int j = 0; j < 8; ++j) h8[j] = f2bf(T[ch * 8 + j][c]);
        uint4 p;
        p.x = (unsigned)h8[0] | ((unsigned)h8[1] << 16);
        p.y = (unsigned)h8[2] | ((unsigned)h8[3] << 16);
        p.z = (unsigned)h8[4] | ((unsigned)h8[5] << 16);
        p.w = (unsigned)h8[6] | ((unsigned)h8[7] << 16);
        *(uint4*)&out[(size_t)(c0 + c) * 1024 + r0 + ch * 8] = p;
    }
}

// ---------------------------------------------------------------------------
// bf16 MFMA GEMM v7 (R5/R8, best measured: 73 µs MODE0).
//   Fragment-register double-buffer pipeline, 3-buffer LDS ring, lookahead 2,
//   counted vmcnt/lgkmcnt, ONE barrier per K-tile, proven-conflict-free
//   swizzle (0 bank conflicts measured R2-R10).
// MODE 0: QKV — BM=128,BN=256, grid 64x12 = 768 (3 CU rounds).
// MODE 1: out — grid 64x4 = 256 (1 CU round).
// ---------------------------------------------------------------------------
template<int MODE>
__global__ __launch_bounds__(512, 2)
void gemm_mfma(const unsigned short* __restrict__ A,
               const unsigned short* __restrict__ Bt,
               const float* __restrict__ bq, const float* __restrict__ bk,
               const float* __restrict__ bv, const float* __restrict__ bo,
               unsigned short* __restrict__ Qb, unsigned short* __restrict__ Kb,
               unsigned short* __restrict__ Vt, float* __restrict__ Cout)
{
    __shared__ short As[3][128 * 64];
    __shared__ short Bs[3][256 * 64];

    const int tid  = threadIdx.x;
    const int w    = tid >> 6, lane = tid & 63;
    const int g    = lane >> 4, l15 = lane & 15;
    const int wm   = w >> 2, wn = w & 3;
    const int mbase = blockIdx.x * 128;
    const int nbase = blockIdx.y * 256;

    const int srow   = lane >> 3;
    const int schunk = (lane & 7) ^ srow;
    const size_t aoff = (size_t)(mbase + srow) * 1024 + schunk * 8;
    const size_t boff = (size_t)(nbase + srow) * 1024 + schunk * 8;

    f32x4 acc[4][4];
    #pragma unroll
    for (int mt = 0; mt < 4; ++mt)
        #pragma unroll
        for (int nt = 0; nt < 4; ++nt)
            acc[mt][nt] = (f32x4){0.f, 0.f, 0.f, 0.f};

    auto STAGE = [&](int t, int buf) {
        #pragma unroll
        for (int i = 0; i < 2; ++i) {
            const int u = w * 2 + i;
            load_lds16(&A[aoff + (size_t)(u * 8) * 1024 + t * 64], &As[buf][u * 512]);
        }
        #pragma unroll
        for (int i = 0; i < 4; ++i) {
            const int u = w * 4 + i;
            load_lds16(&Bt[boff + (size_t)(u * 8) * 1024 + t * 64], &Bs[buf][u * 512]);
        }
    };

    const int pr  = l15 & 7;
    const int pc0 = (g ^ pr) * 8;
    const int pc1 = ((4 + g) ^ pr) * 8;

    s16x8 a0[4], b0[4], a1[4], b1[4];
    auto LDF = [&](s16x8* af, s16x8* bf, int buf, int pc) {
        #pragma unroll
        for (int mt = 0; mt < 4; ++mt)
            af[mt] = *(const s16x8*)&As[buf][(wm * 64 + mt * 16 + l15) * 64 + pc];
        #pragma unroll
        for (int nt = 0; nt < 4; ++nt)
            bf[nt] = *(const s16x8*)&Bs[buf][(wn * 64 + nt * 16 + l15) * 64 + pc];
    };
    auto MFMA16 = [&](const s16x8* af, const s16x8* bf) {
        __builtin_amdgcn_s_setprio(1);
        #pragma unroll
        for (int mt = 0; mt < 4; ++mt)
            #pragma unroll
            for (int nt = 0; nt < 4; ++nt)
                acc[mt][nt] = __builtin_amdgcn_mfma_f32_16x16x32_bf16(
                    af[mt], bf[nt], acc[mt][nt], 0, 0, 0);
        __builtin_amdgcn_s_setprio(0);
    };

    STAGE(0, 0); STAGE(1, 1);
    WAITV(6);
    __builtin_amdgcn_s_barrier();
    LDF(a0, b0, 0, pc0);

    #pragma unroll 1
    for (int t = 0; t < 16; ++t) {
        const int buf = t % 3;
        LDF(a1, b1, buf, pc1);
        if (t + 2 < 16) STAGE(t + 2, (t + 2) % 3);
        WAITL(8); SCHEDB;
        MFMA16(a0, b0);
        WAITL(0); SCHEDB;
        if (t < 15) {
            if (t < 14) { WAITV(6); } else { WAITV(0); }
            __builtin_amdgcn_s_barrier();
            LDF(a0, b0, (t + 1) % 3, pc0);
            WAITL(8); SCHEDB;
        }
        MFMA16(a1, b1);
    }

    #pragma unroll
    for (int nt = 0; nt < 4; ++nt) {
        const int ncol = nbase + wn * 64 + nt * 16 + l15;
        if (MODE == 0) {
            const int tt = ncol >> 10;
            const int hh = (ncol >> 6) & 15;
            const int d  = ncol & 63;
            const float* bias = (tt == 0) ? bq : ((tt == 1) ? bk : bv);
            const float sc = (tt == 0) ? QSCALE : 1.0f;
            const float bval = bias[hh * 64 + d];
            #pragma unroll
            for (int mt = 0; mt < 4; ++mt)
                #pragma unroll
                for (int r = 0; r < 4; ++r) {
                    const int m = mbase + wm * 64 + mt * 16 + g * 4 + r;
                    const int b = m >> 11, s = m & 2047;
                    const unsigned short val = f2bf((acc[mt][nt][r] + bval) * sc);
                    if (tt == 2)
                        Vt[((size_t)(b * 16 + hh) * 64 + d) * 2048 + s] = val;
                    else {
                        unsigned short* Out = (tt == 0) ? Qb : Kb;
                        Out[((size_t)(b * 16 + hh) * 2048 + s) * 64 + d] = val;
                    }
                }
        } else {
            const float bval = bo[ncol];
            #pragma unroll
            for (int mt = 0; mt < 4; ++mt)
                #pragma unroll
                for (int r = 0; r < 4; ++r) {
                    const int m = mbase + wm * 64 + mt * 16 + g * 4 + r;
                    Cout[(size_t)m * 1024 + ncol] = acc[mt][nt][r] + bval;
                }
        }
    }
}

// ---------------------------------------------------------------------------
// MFMA flash attention v8 (R4/R8, best measured). Reg-staged K/V double
// buffer with register prefetch + plain __syncthreads (R9's DMA staging and
// R10's raw-barrier fence both measured slower). cvt_pk bf16 packing,
// ones-MFMA row-sum, raw exp2.
// ---------------------------------------------------------------------------
#define LDK 72
__global__ __launch_bounds__(512, 2)
void attn_mfma(const unsigned short* __restrict__ Qb,
               const unsigned short* __restrict__ Kb,
               const unsigned short* __restrict__ Vt,
               unsigned short* __restrict__ O)
{
    __shared__ short Kls[2][64 * LDK];
    __shared__ short Vls[2][64 * LDK];       // [d][key]
    __shared__ short Pls[8][16 * LDK];       // per-wave P [query][key]

    const int tid  = threadIdx.x;
    const int w    = tid >> 6;               // 0..7
    const int lane = tid & 63;
    const int g    = lane >> 4;
    const int l15  = lane & 15;
    const int j    = blockIdx.x;             // 0..7 (light tile index)
    const int j2   = 15 - j;                 // heavy tile index
    const int h    = blockIdx.y;
    const int b    = blockIdx.z;

    const size_t hb = (size_t)(b * 16 + h) * (2048 * 64);
    const int qH = j2 * 128 + w * 16;        // this wave's heavy query base
    const int qL = j * 128 + w * 16;         // this wave's light query base

    s16x8 aqH[2], aqL[2];
    {
        const int rh = qH + l15, rl = qL + l15;
        aqH[0] = *(const s16x8*)&Qb[hb + (size_t)rh * 64 + g * 8];
        aqH[1] = *(const s16x8*)&Qb[hb + (size_t)rh * 64 + 32 + g * 8];
        aqL[0] = *(const s16x8*)&Qb[hb + (size_t)rl * 64 + g * 8];
        aqL[1] = *(const s16x8*)&Qb[hb + (size_t)rl * 64 + 32 + g * 8];
    }

    // all-ones bf16 A-frag for the row-sum MFMA (bf16 1.0 = 0x3F80)
    const s16x8 ones = (s16x8){(short)0x3F80, (short)0x3F80, (short)0x3F80,
                               (short)0x3F80, (short)0x3F80, (short)0x3F80,
                               (short)0x3F80, (short)0x3F80};

    f32x4 lsumHa = (f32x4){0.f,0.f,0.f,0.f};
    f32x4 lsumLa = (f32x4){0.f,0.f,0.f,0.f};
    f32x4 OH[4], OL[4];                      // O^T: col query, rows d
    #pragma unroll
    for (int nt = 0; nt < 4; ++nt) { OH[nt] = (f32x4){0.f,0.f,0.f,0.f}; OL[nt] = (f32x4){0.f,0.f,0.f,0.f}; }

    const int stages      = 32 - 2 * j;
    const int lightStages = 2 * j + 2;

    const int srow = tid >> 3, spart = tid & 7;
    uint4 kreg = *(const uint4*)&Kb[hb + (size_t)srow * 64 + spart * 8];
    uint4 vreg = *(const uint4*)&Vt[hb + (size_t)srow * 2048 + spart * 8];

    for (int t = 0; t < stages; ++t) {
        const int t0  = t * 64;
        const int buf = t & 1;
        *(uint4*)&Kls[buf][srow * LDK + spart * 8] = kreg;
        *(uint4*)&Vls[buf][srow * LDK + spart * 8] = vreg;
        if (t + 1 < stages) {
            kreg = *(const uint4*)&Kb[hb + (size_t)(t0 + 64 + srow) * 64 + spart * 8];
            vreg = *(const uint4*)&Vt[hb + (size_t)srow * 2048 + t0 + 64 + spart * 8];
        }
        __syncthreads();

        #pragma unroll
        for (int half = 0; half < 2; ++half) {
            if (half == 1 && t >= lightStages) break;
            const s16x8* aq   = (half == 0) ? aqH : aqL;
            const int qbase   = (half == 0) ? qH : qL;
            f32x4* Oacc       = (half == 0) ? OH : OL;
            f32x4* lsa        = (half == 0) ? &lsumHa : &lsumLa;

            // ---- S^T = K * Q^T : Sf[ct][r] = S[query=l15][key=t0+ct*16+g*4+r]
            f32x4 Sf[4];
            #pragma unroll
            for (int ct = 0; ct < 4; ++ct) {
                f32x4 acc = (f32x4){0.f, 0.f, 0.f, 0.f};
                const s16x8 bk0 = *(const s16x8*)&Kls[buf][(ct * 16 + l15) * LDK + g * 8];
                const s16x8 bk1 = *(const s16x8*)&Kls[buf][(ct * 16 + l15) * LDK + 32 + g * 8];
                acc = __builtin_amdgcn_mfma_f32_16x16x32_bf16(bk0, aq[0], acc, 0, 0, 0);
                acc = __builtin_amdgcn_mfma_f32_16x16x32_bf16(bk1, aq[1], acc, 0, 0, 0);
                Sf[ct] = acc;
            }

            // ---- causal mask (diagonal tiles only) ----
            if (t0 + 63 > qbase) {
                const int query = qbase + l15;
                #pragma unroll
                for (int ct = 0; ct < 4; ++ct) {
                    const int kbase = t0 + ct * 16 + g * 4;
                    #pragma unroll
                    for (int r = 0; r < 4; ++r)
                        if (kbase + r > query) Sf[ct][r] = -1e30f;
                }
            }

            // ---- p = exp2(s) ----
            #pragma unroll
            for (int ct = 0; ct < 4; ++ct)
                #pragma unroll
                for (int r = 0; r < 4; ++r) Sf[ct][r] = fast_exp2(Sf[ct][r]);

            // ---- write P[query][key]: cvt_pk (1 VALU per pair) -> b64 ----
            #pragma unroll
            for (int ct = 0; ct < 4; ++ct) {
                uint2 pw;
                pw.x = cvt_pk_bf16(Sf[ct][0], Sf[ct][1]);
                pw.y = cvt_pk_bf16(Sf[ct][2], Sf[ct][3]);
                *(uint2*)&Pls[w][l15 * LDK + ct * 16 + g * 4] = pw;
            }

            // ---- PV: O^T += V^T * P^T; l += 1 * P^T (ones-MFMA row-sum) ----
            const s16x8 pf0 = *(const s16x8*)&Pls[w][l15 * LDK + g * 8];
            const s16x8 pf1 = *(const s16x8*)&Pls[w][l15 * LDK + 32 + g * 8];
            *lsa = __builtin_amdgcn_mfma_f32_16x16x32_bf16(ones, pf0, *lsa, 0, 0, 0);
            *lsa = __builtin_amdgcn_mfma_f32_16x16x32_bf16(ones, pf1, *lsa, 0, 0, 0);
            #pragma unroll
            for (int nt = 0; nt < 4; ++nt) {
                const s16x8 bv0 = *(const s16x8*)&Vls[buf][(nt * 16 + l15) * LDK + g * 8];
                const s16x8 bv1 = *(const s16x8*)&Vls[buf][(nt * 16 + l15) * LDK + 32 + g * 8];
                Oacc[nt] = __builtin_amdgcn_mfma_f32_16x16x32_bf16(bv0, pf0, Oacc[nt], 0, 0, 0);
                Oacc[nt] = __builtin_amdgcn_mfma_f32_16x16x32_bf16(bv1, pf1, Oacc[nt], 0, 0, 0);
            }
        }
    }

    // ---- epilogue: l is complete per-query in every acc reg; store O ----
    const float invH = 1.0f / lsumHa[0];
    const float invL = 1.0f / lsumLa[0];

    #pragma unroll
    for (int half = 0; half < 2; ++half) {
        const f32x4* Oacc = (half == 0) ? OH : OL;
        const float  inv  = (half == 0) ? invH : invL;
        const int query   = ((half == 0) ? qH : qL) + l15;
        #pragma unroll
        for (int nt = 0; nt < 4; ++nt) {
            uint2 pk;
            pk.x = cvt_pk_bf16(Oacc[nt][0] * inv, Oacc[nt][1] * inv);
            pk.y = cvt_pk_bf16(Oacc[nt][2] * inv, Oacc[nt][3] * inv);
            *(uint2*)&O[(size_t)(b * 2048 + query) * 1024 + h * 64 + nt * 16 + g * 4] = pk;
        }
    }
}

// ---------------------------------------------------------------------------
// ws (ushort elems): xb 8M | Wqkvt 3M | Wot 1M | Qb/Kb/Vt 8M each | Ob 8M
// ---------------------------------------------------------------------------
extern "C" void kernel_launch(void* const* d_in, const int* in_sizes, int n_in,
                              void* d_out, int out_size, void* d_ws, size_t ws_size,
                              hipStream_t stream) {
    const float* x  = (const float*)d_in[0];
    const float* wq = (const float*)d_in[1];
    const float* bq = (const float*)d_in[2];
    const float* wk = (const float*)d_in[3];
    const float* bk = (const float*)d_in[4];
    const float* wv = (const float*)d_in[5];
    const float* bv = (const float*)d_in[6];
    const float* wo = (const float*)d_in[7];
    const float* bo = (const float*)d_in[8];
    float* out = (float*)d_out;

    const size_t hsz = (size_t)B_ * H_ * S_ * D_;        // 8388608
    unsigned short* xb    = (unsigned short*)d_ws;
    unsigned short* Wqkvt = xb + hsz;
    unsigned short* Wot   = Wqkvt + (size_t)3072 * 1024;
    unsigned short* Qb    = Wot + (size_t)1024 * 1024;
    unsigned short* Kb    = Qb + hsz;
    unsigned short* Vt    = Kb + hsz;
    unsigned short* Ob    = Vt + hsz;

    preprocess<<<5120, 256, 0, stream>>>(x, wq, wk, wv, wo, xb, Wqkvt, Wot);
    gemm_mfma<0><<<dim3(64, 12), 512, 0, stream>>>(
        xb, Wqkvt, bq, bk, bv, nullptr, Qb, Kb, Vt, nullptr);
    attn_mfma<<<dim3(8, H_, B_), 512, 0, stream>>>(Qb, Kb, Vt, Ob);
    gemm_mfma<1><<<dim3(64, 4), 512, 0, stream>>>(
        Ob, Wot, nullptr, nullptr, nullptr, bo, nullptr, nullptr, nullptr, out);
}